// Round 11
// baseline (584.493 us; speedup 1.0000x reference)
//
#include <hip/hip_runtime.h>
#include <hip/hip_bf16.h>

typedef __hip_bfloat16 BF;
typedef __attribute__((ext_vector_type(8))) short bf16x8;
typedef __attribute__((ext_vector_type(4))) float f32x4;

// B=2, C=128, H=W=128, K=8, STRIDE=2, DIL=2, NH=8, dh=16, HID=170, Hc=Wc=64
// fp32 in / fp32 out. MFMA bf16 GEMMs. R9 chassis (128 thr, 2 cells/block) +
// stride-200 Abuf (bank-conflict fix), register-resident scores, no xvL.

// combined 16-component block reduction (2 waves)
__device__ __forceinline__ void gsum16(float v[16], float* red){
  #pragma unroll
  for(int s = 1; s < 64; s <<= 1){
    #pragma unroll
    for(int i = 0; i < 16; i++) v[i] += __shfl_xor(v[i], s);
  }
  const int wid = threadIdx.x >> 6;
  __syncthreads();
  if((threadIdx.x & 63) == 0){
    #pragma unroll
    for(int i = 0; i < 16; i++) red[wid*16 + i] = v[i];
  }
  __syncthreads();
  #pragma unroll
  for(int i = 0; i < 16; i++) v[i] = red[i] + red[16 + i];
}

// Row-stat reduction for C-layout accumulators (2 waves, per-q4 groups)
__device__ __forceinline__ void rowred(float s1[4], float s2[4], float* red,
                                       int wave, int lane){
  #pragma unroll
  for(int m = 1; m < 16; m <<= 1){
    #pragma unroll
    for(int r = 0; r < 4; r++){ s1[r] += __shfl_xor(s1[r], m); s2[r] += __shfl_xor(s2[r], m); }
  }
  const int q4 = lane >> 4;
  __syncthreads();
  if((lane & 15) == 0){
    #pragma unroll
    for(int r = 0; r < 4; r++){
      red[wave*32 + q4*4 + r]      = s1[r];
      red[wave*32 + 16 + q4*4 + r] = s2[r];
    }
  }
  __syncthreads();
  #pragma unroll
  for(int r = 0; r < 4; r++){
    s1[r] = red[q4*4 + r]      + red[32 + q4*4 + r];
    s2[r] = red[16 + q4*4 + r] + red[48 + q4*4 + r];
  }
}

// ---- K0: tiled transpose x (B,C,H,W) -> xt (B,HW,C) ----
__global__ void k_tin(const float* __restrict__ x, float* __restrict__ xt){
  __shared__ float tile[32][33];
  const int b = blockIdx.z;
  const int pb = blockIdx.x * 32;
  const int cb = blockIdx.y * 32;
  const int tx = threadIdx.x, ty = threadIdx.y;
  #pragma unroll
  for(int r = 0; r < 32; r += 8)
    tile[ty+r][tx] = x[(size_t)(b*128 + cb+ty+r)*16384 + pb + tx];
  __syncthreads();
  #pragma unroll
  for(int r = 0; r < 32; r += 8)
    xt[(size_t)((b<<14) + pb + ty + r)*128 + cb + tx] = tile[tx][ty+r];
}

// ---- K1: pack weights to MFMA-B fragment layout, bf16 ----
__global__ void k_wt(const float* __restrict__ qkv_w, const float* __restrict__ proj_w,
                     const float* __restrict__ fc1_w, const float* __restrict__ fc2_w,
                     BF* __restrict__ pk){
  const int idx = blockIdx.x * 256 + threadIdx.x;
  if(idx >= 112640) return;
  float val;
  if(idx < 49152){
    const int reg = idx >> 14, l = idx & 16383;
    const int j = l & 7, q = (l>>3)&3, n = (l>>5)&127, s = l>>12;
    val = qkv_w[(reg*128 + n)*128 + (s*32 + q*8 + j)];
  } else if(idx < 65536){
    const int l = idx - 49152;
    const int j = l&7, q=(l>>3)&3, n=(l>>5)&127, s=l>>12;
    val = proj_w[n*128 + (s*32+q*8+j)];
  } else if(idx < 88064){
    const int l = idx - 65536;
    const int j = l&7, q=(l>>3)&3, rem = l>>5;
    const int n = rem % 176, s = rem / 176;
    const int k = s*32+q*8+j;
    val = (n < 170) ? fc1_w[n*128 + k] : 0.f;
  } else {
    const int l = idx - 88064;
    const int j = l&7, q=(l>>3)&3, n=(l>>5)&127, s=l>>12;
    const int k = s*32+q*8+j;
    val = (k < 170) ? fc2_w[n*170 + k] : 0.f;
  }
  pk[idx] = __float2bfloat16(val);
}

// ---- K2: coarse k,v via MFMA, M=16 (R10 version, verified) ----
__global__ void __launch_bounds__(128)
k_kv(const float* __restrict__ xt,
     const BF* __restrict__ packK, const BF* __restrict__ packV,
     const float* __restrict__ qkv_b,
     const float* __restrict__ kg, const float* __restrict__ kb,
     const float* __restrict__ n1g, const float* __restrict__ n1b,
     float* __restrict__ kcb, float* __restrict__ vcb){
  __shared__ BF Abuf[16*136];
  __shared__ float red[64];
  const int tid = threadIdx.x, wave = tid>>6, lane = tid&63;
  const int l15 = lane&15, q4 = lane>>4;
  const int bx = blockIdx.x;
  float xv[16];
  #pragma unroll
  for(int r = 0; r < 16; r++){
    const int cp = bx*16 + r;
    const int bb = cp>>12, rm = cp&4095, ic = rm>>6, jc = rm&63;
    xv[r] = xt[((size_t)(bb*16384 + 2*ic*128 + 2*jc))*128 + tid];
  }
  float v[16];
  #pragma unroll
  for(int r = 0; r < 16; r++) v[r] = xv[r];
  #pragma unroll
  for(int s = 1; s < 64; s <<= 1){
    #pragma unroll
    for(int r = 0; r < 16; r++) v[r] += __shfl_xor(v[r], s);
  }
  __syncthreads();
  if(lane == 0){ for(int r = 0; r < 16; r++) red[wave*16 + r] = v[r]; }
  __syncthreads();
  #pragma unroll
  for(int r = 0; r < 16; r++) v[r] = red[r] + red[16 + r];
  float xc[16], sq[16];
  #pragma unroll
  for(int r = 0; r < 16; r++){ xc[r] = xv[r] - v[r]*(1.f/128.f); sq[r] = xc[r]*xc[r]; }
  #pragma unroll
  for(int s = 1; s < 64; s <<= 1){
    #pragma unroll
    for(int r = 0; r < 16; r++) sq[r] += __shfl_xor(sq[r], s);
  }
  __syncthreads();
  if(lane == 0){ for(int r = 0; r < 16; r++) red[wave*16 + r] = sq[r]; }
  __syncthreads();
  #pragma unroll
  for(int r = 0; r < 16; r++) sq[r] = red[r] + red[16 + r];
  {
    const float g = n1g[tid], be = n1b[tid];
    #pragma unroll
    for(int r = 0; r < 16; r++)
      Abuf[r*136 + tid] = __float2bfloat16(xc[r]*rsqrtf(sq[r]*(1.f/128.f)+1e-6f)*g + be);
  }
  __syncthreads();
  bf16x8 af[4];
  #pragma unroll
  for(int s = 0; s < 4; s++) af[s] = *(const bf16x8*)&Abuf[l15*136 + s*32 + q4*8];

  f32x4 ka[4];
  #pragma unroll
  for(int nt = 0; nt < 4; nt++){ ka[nt][0]=0.f; ka[nt][1]=0.f; ka[nt][2]=0.f; ka[nt][3]=0.f; }
  #pragma unroll
  for(int nt = 0; nt < 4; nt++){
    const int col = (wave*4+nt)*16 + l15;
    #pragma unroll
    for(int s = 0; s < 4; s++){
      bf16x8 bw = *(const bf16x8*)&packK[((s*128 + col)*4 + q4)*8];
      ka[nt] = __builtin_amdgcn_mfma_f32_16x16x32_bf16(af[s], bw, ka[nt], 0,0,0);
    }
  }
  float s1[4], s2[4];
  #pragma unroll
  for(int r = 0; r < 4; r++){ s1[r]=0.f; s2[r]=0.f; }
  #pragma unroll
  for(int nt = 0; nt < 4; nt++){
    const float cb2 = qkv_b[128 + (wave*4+nt)*16 + l15];
    #pragma unroll
    for(int r = 0; r < 4; r++){
      const float vv = ka[nt][r] + cb2;
      ka[nt][r] = vv; s1[r] += vv; s2[r] += vv*vv;
    }
  }
  rowred(s1, s2, red, wave, lane);
  #pragma unroll
  for(int nt = 0; nt < 4; nt++){
    const int col = (wave*4+nt)*16 + l15;
    const float g = kg[col], be = kb[col];
    #pragma unroll
    for(int r = 0; r < 4; r++){
      const float mu = s1[r]*(1.f/128.f);
      const float var = s2[r]*(1.f/128.f) - mu*mu;
      kcb[(size_t)(bx*16 + q4*4 + r)*128 + col] = (ka[nt][r]-mu)*rsqrtf(var+1e-6f)*g + be;
    }
  }
  #pragma unroll
  for(int nt = 0; nt < 4; nt++){ ka[nt][0]=0.f; ka[nt][1]=0.f; ka[nt][2]=0.f; ka[nt][3]=0.f; }
  #pragma unroll
  for(int nt = 0; nt < 4; nt++){
    const int col = (wave*4+nt)*16 + l15;
    #pragma unroll
    for(int s = 0; s < 4; s++){
      bf16x8 bw = *(const bf16x8*)&packV[((s*128 + col)*4 + q4)*8];
      ka[nt] = __builtin_amdgcn_mfma_f32_16x16x32_bf16(af[s], bw, ka[nt], 0,0,0);
    }
  }
  #pragma unroll
  for(int nt = 0; nt < 4; nt++){
    const int col = (wave*4+nt)*16 + l15;
    const float bv = qkv_b[256 + col];
    #pragma unroll
    for(int r = 0; r < 4; r++)
      vcb[(size_t)(bx*16 + q4*4 + r)*128 + col] = ka[nt][r] + bv;
  }
}

// ---- K3: fused per-2-cells (8 pixels), R9 chassis + fixes ----
__global__ void __launch_bounds__(128)
k_cell(const float* __restrict__ xt_in,
       const BF* __restrict__ packQ, const BF* __restrict__ packP,
       const BF* __restrict__ packF1, const BF* __restrict__ packF2,
       const float* __restrict__ qkv_b,
       const float* __restrict__ qg, const float* __restrict__ qb,
       const float* __restrict__ n1g, const float* __restrict__ n1b,
       const float* __restrict__ proj_b,
       const float* __restrict__ ls1, const float* __restrict__ ls2,
       const float* __restrict__ n2g, const float* __restrict__ n2b,
       const float* __restrict__ fc1_b,
       const float* __restrict__ mg, const float* __restrict__ mb,
       const float* __restrict__ fc2_b,
       const float* __restrict__ kcb, const float* __restrict__ vcb,
       float* __restrict__ xt_out){
  __shared__ BF Abuf[16*200];      // stride 200 bf16 = 400 B -> 2-way banks (free)
  __shared__ float4 qnP[2*136];    // [cell][head*17 + d]
  __shared__ float4 sc4[512];      // probs of one cell at a time
  __shared__ int cidxA[64], cidxB[64];
  __shared__ float red[64];
  const int tid = threadIdx.x, wave = tid>>6, lane = tid&63;
  const int l15 = lane&15, q4 = lane>>4;
  { uint32_t* az = (uint32_t*)Abuf; for(int i = tid; i < 1600; i += 128) az[i] = 0u; }

  const int bx = blockIdx.x;
  const int b = bx >> 11, rem = bx & 2047, ip = rem >> 6, jc = rem & 63;
  const int icA = 2*ip, icB = 2*ip + 1;
  const size_t base = (size_t)b * 16384 * 128;
  size_t p[8];
  {
    const int h0 = 4*ip;
    p[0] = base + ((size_t)(h0*128     + 2*jc    ))*128;
    p[1] = base + ((size_t)(h0*128     + 2*jc + 1))*128;
    p[2] = base + ((size_t)((h0+1)*128 + 2*jc    ))*128;
    p[3] = base + ((size_t)((h0+1)*128 + 2*jc + 1))*128;
    p[4] = base + ((size_t)((h0+2)*128 + 2*jc    ))*128;
    p[5] = base + ((size_t)((h0+2)*128 + 2*jc + 1))*128;
    p[6] = base + ((size_t)((h0+3)*128 + 2*jc    ))*128;
    p[7] = base + ((size_t)((h0+3)*128 + 2*jc + 1))*128;
  }

  // ---- LN1 (combined sum+sumsq, one reduction) ----
  {
    float xv[8];
    #pragma unroll
    for(int r = 0; r < 8; r++) xv[r] = xt_in[p[r] + tid];
    float st[16];
    #pragma unroll
    for(int r = 0; r < 8; r++){ st[r] = xv[r]; st[8+r] = xv[r]*xv[r]; }
    gsum16(st, red);
    const float g = n1g[tid], be = n1b[tid];
    #pragma unroll
    for(int r = 0; r < 8; r++){
      const float mu = st[r]*(1.f/128.f);
      const float var = st[8+r]*(1.f/128.f) - mu*mu;
      Abuf[r*200 + tid] = __float2bfloat16((xv[r]-mu)*rsqrtf(var+1e-6f)*g + be);
    }
  }
  if(tid < 64){
    const int i = tid >> 3, j = tid & 7;
    const int rj = jc + 2*j - 8;
    const bool vj = (rj >= 0) && (rj < 64);
    const int riA = icA + 2*i - 8, riB = icB + 2*i - 8;
    cidxA[tid] = (vj && riA >= 0 && riA < 64) ? ((b*4096 + riA*64 + rj)*128) : -1;
    cidxB[tid] = (vj && riB >= 0 && riB < 64) ? ((b*4096 + riB*64 + rj)*128) : -1;
  }
  __syncthreads();

  // ---- q GEMM + q-LN -> qnP ----
  {
    bf16x8 af[4];
    #pragma unroll
    for(int s = 0; s < 4; s++) af[s] = *(const bf16x8*)&Abuf[l15*200 + s*32 + q4*8];
    f32x4 acc[4];
    #pragma unroll
    for(int nt = 0; nt < 4; nt++){ acc[nt][0]=0.f; acc[nt][1]=0.f; acc[nt][2]=0.f; acc[nt][3]=0.f; }
    #pragma unroll
    for(int nt = 0; nt < 4; nt++){
      const int n = (wave*4+nt)*16 + l15;
      #pragma unroll
      for(int s = 0; s < 4; s++){
        bf16x8 bw = *(const bf16x8*)&packQ[((s*128 + n)*4 + q4)*8];
        acc[nt] = __builtin_amdgcn_mfma_f32_16x16x32_bf16(af[s], bw, acc[nt], 0,0,0);
      }
    }
    float s1[4], s2[4];
    #pragma unroll
    for(int r = 0; r < 4; r++){ s1[r]=0.f; s2[r]=0.f; }
    #pragma unroll
    for(int nt = 0; nt < 4; nt++){
      const float cb2 = qkv_b[(wave*4+nt)*16 + l15];
      #pragma unroll
      for(int r = 0; r < 4; r++){
        const float vv = acc[nt][r] + cb2;
        acc[nt][r] = vv; s1[r] += vv; s2[r] += vv*vv;
      }
    }
    rowred(s1, s2, red, wave, lane);
    if(q4 < 2){
      float mu[4], rs[4];
      #pragma unroll
      for(int r = 0; r < 4; r++){
        mu[r] = s1[r]*(1.f/128.f);
        rs[r] = rsqrtf(s2[r]*(1.f/128.f) - mu[r]*mu[r] + 1e-6f);
      }
      #pragma unroll
      for(int nt = 0; nt < 4; nt++){
        const int n = wave*4 + nt;
        const int col = n*16 + l15;
        const float g = qg[col], be = qb[col];
        float4 t;
        t.x = (acc[nt][0]-mu[0])*rs[0]*g + be;
        t.y = (acc[nt][1]-mu[1])*rs[1]*g + be;
        t.z = (acc[nt][2]-mu[2])*rs[2]*g + be;
        t.w = (acc[nt][3]-mu[3])*rs[3]*g + be;
        qnP[q4*136 + n*17 + l15] = t;
      }
    }
  }
  __syncthreads();

  // ---- attention: register-resident scores, sc4 only for probs ----
  float4 oA, oB;
  {
    const int n = tid >> 4, l = tid & 15;
    int ciA4[4], ciB4[4]; bool vA[4], vB[4];
    #pragma unroll
    for(int k = 0; k < 4; k++){
      const int cA = cidxA[l + 16*k], cB = cidxB[l + 16*k];
      vA[k] = (cA >= 0); ciA4[k] = vA[k] ? cA : 0;
      vB[k] = (cB >= 0); ciB4[k] = vB[k] ? cB : 0;
    }
    float4 sA[4], sB[4];
    #pragma unroll
    for(int k = 0; k < 4; k++){
      sA[k].x=0.f; sA[k].y=0.f; sA[k].z=0.f; sA[k].w=0.f;
      sB[k].x=0.f; sB[k].y=0.f; sB[k].z=0.f; sB[k].w=0.f;
    }
    #pragma unroll
    for(int d = 0; d < 16; d++){
      const float4 qA = qnP[n*17 + d];
      const float4 qB = qnP[136 + n*17 + d];
      #pragma unroll
      for(int k = 0; k < 4; k++){
        const float kA = kcb[ciA4[k] + n*16 + d];
        const float kB = kcb[ciB4[k] + n*16 + d];
        sA[k].x += qA.x*kA; sA[k].y += qA.y*kA; sA[k].z += qA.z*kA; sA[k].w += qA.w*kA;
        sB[k].x += qB.x*kB; sB[k].y += qB.y*kB; sB[k].z += qB.z*kB; sB[k].w += qB.w*kB;
      }
    }
    #pragma unroll
    for(int k = 0; k < 4; k++){
      if(vA[k]){ sA[k].x *= 0.25f; sA[k].y *= 0.25f; sA[k].z *= 0.25f; sA[k].w *= 0.25f; }
      else { sA[k].x = -1e30f; sA[k].y = -1e30f; sA[k].z = -1e30f; sA[k].w = -1e30f; }
      if(vB[k]){ sB[k].x *= 0.25f; sB[k].y *= 0.25f; sB[k].z *= 0.25f; sB[k].w *= 0.25f; }
      else { sB[k].x = -1e30f; sB[k].y = -1e30f; sB[k].z = -1e30f; sB[k].w = -1e30f; }
    }
    // softmax A (over 4 slots + 16 lanes of head group)
    #pragma unroll
    for(int cell = 0; cell < 2; cell++){
      float4* s = cell ? sB : sA;
      float4 m = s[0];
      #pragma unroll
      for(int k = 1; k < 4; k++){
        m.x = fmaxf(m.x, s[k].x); m.y = fmaxf(m.y, s[k].y);
        m.z = fmaxf(m.z, s[k].z); m.w = fmaxf(m.w, s[k].w);
      }
      #pragma unroll
      for(int msk = 1; msk < 16; msk <<= 1){
        m.x = fmaxf(m.x, __shfl_xor(m.x, msk));
        m.y = fmaxf(m.y, __shfl_xor(m.y, msk));
        m.z = fmaxf(m.z, __shfl_xor(m.z, msk));
        m.w = fmaxf(m.w, __shfl_xor(m.w, msk));
      }
      float4 es; es.x=0.f; es.y=0.f; es.z=0.f; es.w=0.f;
      #pragma unroll
      for(int k = 0; k < 4; k++){
        s[k].x = __expf(s[k].x - m.x); s[k].y = __expf(s[k].y - m.y);
        s[k].z = __expf(s[k].z - m.z); s[k].w = __expf(s[k].w - m.w);
        es.x += s[k].x; es.y += s[k].y; es.z += s[k].z; es.w += s[k].w;
      }
      #pragma unroll
      for(int msk = 1; msk < 16; msk <<= 1){
        es.x += __shfl_xor(es.x, msk); es.y += __shfl_xor(es.y, msk);
        es.z += __shfl_xor(es.z, msk); es.w += __shfl_xor(es.w, msk);
      }
      const float4 inv = {1.f/es.x, 1.f/es.y, 1.f/es.z, 1.f/es.w};
      #pragma unroll
      for(int k = 0; k < 4; k++){
        s[k].x *= inv.x; s[k].y *= inv.y; s[k].z *= inv.z; s[k].w *= inv.w;
      }
    }
    // PV cell A
    #pragma unroll
    for(int k = 0; k < 4; k++) sc4[n*64 + l + 16*k] = sA[k];
    __syncthreads();
    {
      float4 o; o.x=0.f; o.y=0.f; o.z=0.f; o.w=0.f;
      for(int nb = 0; nb < 64; nb++){
        const int ci = cidxA[nb];
        if(ci >= 0){
          const float vv = vcb[ci + tid];
          const float4 pr = sc4[n*64 + nb];
          o.x += pr.x*vv; o.y += pr.y*vv; o.z += pr.z*vv; o.w += pr.w*vv;
        }
      }
      oA = o;
    }
    __syncthreads();
    // PV cell B
    #pragma unroll
    for(int k = 0; k < 4; k++) sc4[n*64 + l + 16*k] = sB[k];
    __syncthreads();
    {
      float4 o; o.x=0.f; o.y=0.f; o.z=0.f; o.w=0.f;
      for(int nb = 0; nb < 64; nb++){
        const int ci = cidxB[nb];
        if(ci >= 0){
          const float vv = vcb[ci + tid];
          const float4 pr = sc4[n*64 + nb];
          o.x += pr.x*vv; o.y += pr.y*vv; o.z += pr.z*vv; o.w += pr.w*vv;
        }
      }
      oB = o;
    }
  }
  // ao -> Abuf (A of proj)
  Abuf[0*200 + tid] = __float2bfloat16(oA.x);
  Abuf[1*200 + tid] = __float2bfloat16(oA.y);
  Abuf[2*200 + tid] = __float2bfloat16(oA.z);
  Abuf[3*200 + tid] = __float2bfloat16(oA.w);
  Abuf[4*200 + tid] = __float2bfloat16(oB.x);
  Abuf[5*200 + tid] = __float2bfloat16(oB.y);
  Abuf[6*200 + tid] = __float2bfloat16(oB.z);
  Abuf[7*200 + tid] = __float2bfloat16(oB.w);
  __syncthreads();

  // ---- proj GEMM + ls1*res -> xh ; LN2 -> Abuf ----
  float xh[4][4];
  {
    bf16x8 af[4];
    #pragma unroll
    for(int s = 0; s < 4; s++) af[s] = *(const bf16x8*)&Abuf[l15*200 + s*32 + q4*8];
    f32x4 acc[4];
    #pragma unroll
    for(int nt = 0; nt < 4; nt++){ acc[nt][0]=0.f; acc[nt][1]=0.f; acc[nt][2]=0.f; acc[nt][3]=0.f; }
    #pragma unroll
    for(int nt = 0; nt < 4; nt++){
      const int n = (wave*4+nt)*16 + l15;
      #pragma unroll
      for(int s = 0; s < 4; s++){
        bf16x8 bw = *(const bf16x8*)&packP[((s*128 + n)*4 + q4)*8];
        acc[nt] = __builtin_amdgcn_mfma_f32_16x16x32_bf16(af[s], bw, acc[nt], 0,0,0);
      }
    }
    float s1[4], s2[4];
    #pragma unroll
    for(int r = 0; r < 4; r++){ s1[r]=0.f; s2[r]=0.f; }
    #pragma unroll
    for(int nt = 0; nt < 4; nt++){
      const int col = (wave*4+nt)*16 + l15;
      const float bp = proj_b[col], l1 = ls1[col];
      #pragma unroll
      for(int r = 0; r < 4; r++){
        const int row = q4*4 + r;
        const float xvv = (row < 8) ? xt_in[p[row] + col] : 0.f;
        const float hx = xvv + l1*(acc[nt][r] + bp);
        xh[nt][r] = hx; s1[r] += hx; s2[r] += hx*hx;
      }
    }
    rowred(s1, s2, red, wave, lane);
    #pragma unroll
    for(int nt = 0; nt < 4; nt++){
      const int col = (wave*4+nt)*16 + l15;
      const float g = n2g[col], be = n2b[col];
      #pragma unroll
      for(int r = 0; r < 4; r++){
        const int row = q4*4 + r;
        if(row < 8){
          const float mu = s1[r]*(1.f/128.f);
          const float var = s2[r]*(1.f/128.f) - mu*mu;
          Abuf[row*200 + col] =
            __float2bfloat16((xh[nt][r]-mu)*rsqrtf(var+1e-6f)*g + be);
        }
      }
    }
  }
  __syncthreads();

  // ---- fc1 GEMM (N=176) + midLN + gelu -> Abuf ----
  {
    bf16x8 af[4];
    #pragma unroll
    for(int s = 0; s < 4; s++) af[s] = *(const bf16x8*)&Abuf[l15*200 + s*32 + q4*8];
    const int NT1 = wave ? 5 : 6;
    f32x4 acc1[6];
    #pragma unroll
    for(int nt = 0; nt < 6; nt++){ acc1[nt][0]=0.f; acc1[nt][1]=0.f; acc1[nt][2]=0.f; acc1[nt][3]=0.f; }
    for(int nt = 0; nt < NT1; nt++){
      const int tI = wave ? (6 + nt) : nt;
      const int n = tI*16 + l15;
      #pragma unroll
      for(int s = 0; s < 4; s++){
        bf16x8 bw = *(const bf16x8*)&packF1[((s*176 + n)*4 + q4)*8];
        acc1[nt] = __builtin_amdgcn_mfma_f32_16x16x32_bf16(af[s], bw, acc1[nt], 0,0,0);
      }
    }
    float s1[4], s2[4];
    #pragma unroll
    for(int r = 0; r < 4; r++){ s1[r]=0.f; s2[r]=0.f; }
    for(int nt = 0; nt < NT1; nt++){
      const int tI = wave ? (6 + nt) : nt;
      const int col = tI*16 + l15;
      const float b1 = (col < 170) ? fc1_b[col] : 0.f;
      #pragma unroll
      for(int r = 0; r < 4; r++){
        const float vv = acc1[nt][r] + b1;
        acc1[nt][r] = vv;
        if(col < 170){ s1[r] += vv; s2[r] += vv*vv; }
      }
    }
    rowred(s1, s2, red, wave, lane);
    const float kA = 0.7978845608028654f, kB = 0.044715f;
    for(int nt = 0; nt < NT1; nt++){
      const int tI = wave ? (6 + nt) : nt;
      const int col = tI*16 + l15;
      if(col < 170){
        const float g = mg[col], be = mb[col];
        #pragma unroll
        for(int r = 0; r < 4; r++){
          const int row = q4*4 + r;
          if(row < 8){
            const float mu = s1[r]*(1.f/170.f);
            const float var = s2[r]*(1.f/170.f) - mu*mu;
            const float hn = (acc1[nt][r]-mu)*rsqrtf(var+1e-6f)*g + be;
            const float gl = 0.5f*hn*(1.f + tanhf(kA*(hn + kB*hn*hn*hn)));
            Abuf[row*200 + col] = __float2bfloat16(gl);
          }
        }
      }
    }
  }
  __syncthreads();

  // ---- fc2 GEMM (K=192) + ls2*res -> xt ----
  {
    bf16x8 af[6];
    #pragma unroll
    for(int s = 0; s < 6; s++) af[s] = *(const bf16x8*)&Abuf[l15*200 + s*32 + q4*8];
    f32x4 acc[4];
    #pragma unroll
    for(int nt = 0; nt < 4; nt++){ acc[nt][0]=0.f; acc[nt][1]=0.f; acc[nt][2]=0.f; acc[nt][3]=0.f; }
    #pragma unroll
    for(int nt = 0; nt < 4; nt++){
      const int n = (wave*4+nt)*16 + l15;
      #pragma unroll
      for(int s = 0; s < 6; s++){
        bf16x8 bw = *(const bf16x8*)&packF2[((s*128 + n)*4 + q4)*8];
        acc[nt] = __builtin_amdgcn_mfma_f32_16x16x32_bf16(af[s], bw, acc[nt], 0,0,0);
      }
    }
    #pragma unroll
    for(int nt = 0; nt < 4; nt++){
      const int col = (wave*4+nt)*16 + l15;
      const float bf2 = fc2_b[col], l2 = ls2[col];
      #pragma unroll
      for(int r = 0; r < 4; r++){
        const int row = q4*4 + r;
        if(row < 8)
          xt_out[p[row] + col] = xh[nt][r] + l2*(acc[nt][r] + bf2);
      }
    }
  }
}

// ---- K4: tiled transpose xt (B,HW,C) -> out (B,C,H,W) ----
__global__ void k_tout(const float* __restrict__ xt, float* __restrict__ out){
  __shared__ float tile[32][33];
  const int b = blockIdx.z;
  const int pb = blockIdx.x * 32;
  const int cb = blockIdx.y * 32;
  const int tx = threadIdx.x, ty = threadIdx.y;
  #pragma unroll
  for(int r = 0; r < 32; r += 8)
    tile[ty+r][tx] = xt[(size_t)((b<<14) + pb + ty + r)*128 + cb + tx];
  __syncthreads();
  #pragma unroll
  for(int r = 0; r < 32; r += 8)
    out[(size_t)(b*128 + cb + ty + r)*16384 + pb + tx] = tile[tx][ty+r];
}

extern "C" void kernel_launch(void* const* d_in, const int* in_sizes, int n_in,
                              void* d_out, int out_size, void* d_ws, size_t ws_size,
                              hipStream_t stream){
  const float* x      = (const float*)d_in[0];
  const float* qkv_w  = (const float*)d_in[1];
  const float* qkv_b  = (const float*)d_in[2];
  const float* qg     = (const float*)d_in[3];
  const float* qb     = (const float*)d_in[4];
  const float* kg     = (const float*)d_in[5];
  const float* kb     = (const float*)d_in[6];
  const float* proj_w = (const float*)d_in[7];
  const float* proj_b = (const float*)d_in[8];
  const float* n1g    = (const float*)d_in[9];
  const float* n1b    = (const float*)d_in[10];
  const float* n2g    = (const float*)d_in[11];
  const float* n2b    = (const float*)d_in[12];
  const float* ls1    = (const float*)d_in[13];
  const float* ls2    = (const float*)d_in[14];
  const float* fc1_w  = (const float*)d_in[15];
  const float* fc1_b  = (const float*)d_in[16];
  const float* mg     = (const float*)d_in[17];
  const float* mb     = (const float*)d_in[18];
  const float* fc2_w  = (const float*)d_in[19];
  const float* fc2_b  = (const float*)d_in[20];

  float* ws  = (float*)d_ws;
  float* xt  = ws;
  float* kcb = ws + 4194304;
  float* vcb = ws + 5242880;
  BF* pk     = (BF*)(ws + 6291456);
  BF* packQ  = pk;
  BF* packK  = pk + 16384;
  BF* packV  = pk + 32768;
  BF* packP  = pk + 49152;
  BF* packF1 = pk + 65536;
  BF* packF2 = pk + 88064;

  dim3 tgrid(512, 4, 2), tblk(32, 8);
  k_tin <<<tgrid, tblk, 0, stream>>>(x, xt);
  k_wt  <<<440, 256, 0, stream>>>(qkv_w, proj_w, fc1_w, fc2_w, pk);
  k_kv  <<<512, 128, 0, stream>>>(xt, packK, packV, qkv_b, kg, kb, n1g, n1b, kcb, vcb);
  k_cell<<<4096, 128, 0, stream>>>(xt, packQ, packP, packF1, packF2,
                                   qkv_b, qg, qb, n1g, n1b, proj_b, ls1, ls2,
                                   n2g, n2b, fc1_b, mg, mb, fc2_b,
                                   kcb, vcb, xt);
  k_tout<<<tgrid, tblk, 0, stream>>>(xt, (float*)d_out);
}